// Round 1
// baseline (28704.230 us; speedup 1.0000x reference)
//
#include <hip/hip_runtime.h>
#include <math.h>

// BiometricLSTM: 2-layer LSTM, B=512, T=2048, I=3, H=64, fp32, output = final h of layer 2 (B,64).
//
// Strategy: fused persistent kernel. 256 blocks x 512 threads, 1 block/CU, one pass.
//  - Each block owns P=2 sequences (batch b = 2*blockIdx + {0,1}).
//  - Threads [0,256): layer-0 gate g; threads [256,512): layer-1 gate g. Each thread
//    computes its gate for both sequences (weight-register reuse across P).
//  - Weights in VGPRs (loaded once; LDS can't feed per-lane-distinct W rows at rate).
//  - h state in LDS, read as wave-uniform float4 broadcasts (conflict-free).
//  - Layers software-pipelined with 1-step lag: iteration it computes layer0 step it
//    and layer1 step it-1 concurrently; 2 barriers/step.
//  - c state in registers of wave-aligned update threads (0-127 of each group).

constexpr int TT = 2048;
constexpr int HH = 64;

__device__ __forceinline__ float fast_sigmoid(float x) {
    return 1.0f / (1.0f + __expf(-x));
}

// overflow-safe tanh: c can reach O(100s); exp(-2|x|) underflows harmlessly to 0 -> +/-1
__device__ __forceinline__ float fast_tanh(float x) {
    float ax = fabsf(x);
    float t  = __expf(-2.0f * ax);
    float r  = (1.0f - t) / (1.0f + t);
    return copysignf(r, x);
}

__global__ __launch_bounds__(512, 2) void lstm2_fused(
    const float* __restrict__ x,
    const float* __restrict__ Wih0, const float* __restrict__ Whh0,
    const float* __restrict__ bih0, const float* __restrict__ bhh0,
    const float* __restrict__ Wih1, const float* __restrict__ Whh1,
    const float* __restrict__ bih1, const float* __restrict__ bhh1,
    float* __restrict__ out)
{
    __shared__ __align__(16) float xs[2 * TT * 3];      // 48 KB: x for both sequences
    __shared__ __align__(16) float h1buf[2][2][HH];     // [parity][seq][h]
    __shared__ __align__(16) float h2buf[2][2][HH];
    __shared__ __align__(16) float gbuf[2][2][256];     // [layer][seq][gate] (activated)

    const int tid   = threadIdx.x;
    const int group = tid >> 8;        // 0 = layer0 gates, 1 = layer1 gates
    const int g     = tid & 255;

    // ---- preload x (coalesced, one-time): 2*2048*3 = 12288 floats = 3072 float4 ----
    {
        const float4* src = (const float4*)(x + (size_t)blockIdx.x * (2 * TT * 3));
        float4* dst = (float4*)xs;
        #pragma unroll
        for (int i = 0; i < 6; ++i) dst[tid + i * 512] = src[tid + i * 512];
    }
    // ---- zero h double-buffers (256 floats each) ----
    if (tid < 256)       ((float*)h1buf)[tid] = 0.0f;
    else                 ((float*)h2buf)[tid - 256] = 0.0f;

    // ---- load this thread's weight rows into registers ----
    float w0[64];            // group0: Whh0 row g   | group1: Wih1 row g
    float w1[64];            // group1 only: Whh1 row g
    float wx0 = 0.f, wx1 = 0.f, wx2 = 0.f;
    float bias;
    if (group == 0) {
        const float4* wr = (const float4*)(Whh0 + g * HH);
        #pragma unroll
        for (int k4 = 0; k4 < 16; ++k4) {
            float4 v = wr[k4];
            w0[4*k4+0] = v.x; w0[4*k4+1] = v.y; w0[4*k4+2] = v.z; w0[4*k4+3] = v.w;
        }
        wx0 = Wih0[g*3+0]; wx1 = Wih0[g*3+1]; wx2 = Wih0[g*3+2];
        bias = bih0[g] + bhh0[g];
    } else {
        const float4* wa = (const float4*)(Wih1 + g * HH);
        const float4* wb = (const float4*)(Whh1 + g * HH);
        #pragma unroll
        for (int k4 = 0; k4 < 16; ++k4) {
            float4 v = wa[k4];
            w0[4*k4+0] = v.x; w0[4*k4+1] = v.y; w0[4*k4+2] = v.z; w0[4*k4+3] = v.w;
            float4 u = wb[k4];
            w1[4*k4+0] = u.x; w1[4*k4+1] = u.y; w1[4*k4+2] = u.z; w1[4*k4+3] = u.w;
        }
        bias = bih1[g] + bhh1[g];
    }

    // update-thread identity (threads 0-127 of each group): (seq, j)
    const int s_upd = (g >> 6) & 1;
    const int j_upd = g & 63;
    float c_state = 0.0f;

    __syncthreads();

    // iteration it: layer0 computes step it (it < T); layer1 computes step it-1 (it >= 1)
    for (int it = 0; it <= TT; ++it) {
        const int cur  = it & 1;
        const int prev = cur ^ 1;

        // ---------------- phase 1: gate GEMVs (both layer groups concurrently) -------------
        if (group == 0) {
            if (it < TT) {
                float a0=0.f,b0=0.f,c0=0.f,d0=0.f, a1=0.f,b1=0.f,c1=0.f,d1=0.f;
                const float4* h0p = (const float4*)h1buf[prev][0];   // uniform broadcast
                const float4* h1p = (const float4*)h1buf[prev][1];
                #pragma unroll
                for (int k4 = 0; k4 < 16; ++k4) {
                    float4 hv0 = h0p[k4];
                    float4 hv1 = h1p[k4];
                    a0 = fmaf(w0[4*k4+0], hv0.x, a0); b0 = fmaf(w0[4*k4+1], hv0.y, b0);
                    c0 = fmaf(w0[4*k4+2], hv0.z, c0); d0 = fmaf(w0[4*k4+3], hv0.w, d0);
                    a1 = fmaf(w0[4*k4+0], hv1.x, a1); b1 = fmaf(w0[4*k4+1], hv1.y, b1);
                    c1 = fmaf(w0[4*k4+2], hv1.z, c1); d1 = fmaf(w0[4*k4+3], hv1.w, d1);
                }
                const int xb = it * 3;
                float gate0 = bias + (a0+b0) + (c0+d0)
                            + wx0*xs[xb] + wx1*xs[xb+1] + wx2*xs[xb+2];
                float gate1 = bias + (a1+b1) + (c1+d1)
                            + wx0*xs[6144+xb] + wx1*xs[6144+xb+1] + wx2*xs[6144+xb+2];
                if ((g >> 6) == 2) { gate0 = fast_tanh(gate0);    gate1 = fast_tanh(gate1); }
                else              { gate0 = fast_sigmoid(gate0); gate1 = fast_sigmoid(gate1); }
                gbuf[0][0][g] = gate0;
                gbuf[0][1][g] = gate1;
            }
        } else {
            if (it >= 1) {
                // layer1 step t1 = it-1: inputs h1[t1] = h1buf[prev], h2[t1-1] = h2buf[cur]
                float a0=0.f,b0=0.f,c0=0.f,d0=0.f, a1=0.f,b1=0.f,c1=0.f,d1=0.f;
                const float4* i0p = (const float4*)h1buf[prev][0];
                const float4* i1p = (const float4*)h1buf[prev][1];
                const float4* r0p = (const float4*)h2buf[cur][0];
                const float4* r1p = (const float4*)h2buf[cur][1];
                #pragma unroll
                for (int k4 = 0; k4 < 16; ++k4) {
                    float4 hv0 = i0p[k4];
                    float4 hv1 = i1p[k4];
                    a0 = fmaf(w0[4*k4+0], hv0.x, a0); b0 = fmaf(w0[4*k4+1], hv0.y, b0);
                    c0 = fmaf(w0[4*k4+2], hv0.z, c0); d0 = fmaf(w0[4*k4+3], hv0.w, d0);
                    a1 = fmaf(w0[4*k4+0], hv1.x, a1); b1 = fmaf(w0[4*k4+1], hv1.y, b1);
                    c1 = fmaf(w0[4*k4+2], hv1.z, c1); d1 = fmaf(w0[4*k4+3], hv1.w, d1);
                }
                #pragma unroll
                for (int k4 = 0; k4 < 16; ++k4) {
                    float4 hv0 = r0p[k4];
                    float4 hv1 = r1p[k4];
                    a0 = fmaf(w1[4*k4+0], hv0.x, a0); b0 = fmaf(w1[4*k4+1], hv0.y, b0);
                    c0 = fmaf(w1[4*k4+2], hv0.z, c0); d0 = fmaf(w1[4*k4+3], hv0.w, d0);
                    a1 = fmaf(w1[4*k4+0], hv1.x, a1); b1 = fmaf(w1[4*k4+1], hv1.y, b1);
                    c1 = fmaf(w1[4*k4+2], hv1.z, c1); d1 = fmaf(w1[4*k4+3], hv1.w, d1);
                }
                float gate0 = bias + (a0+b0) + (c0+d0);
                float gate1 = bias + (a1+b1) + (c1+d1);
                if ((g >> 6) == 2) { gate0 = fast_tanh(gate0);    gate1 = fast_tanh(gate1); }
                else              { gate0 = fast_sigmoid(gate0); gate1 = fast_sigmoid(gate1); }
                gbuf[1][0][g] = gate0;
                gbuf[1][1][g] = gate1;
            }
        }
        __syncthreads();

        // ---------------- phase 2: state update (wave-aligned: threads 0-127 of each group) ----
        if (g < 128) {
            if (group == 0) {
                if (it < TT) {
                    float iv = gbuf[0][s_upd][      j_upd];
                    float fv = gbuf[0][s_upd][ 64 + j_upd];
                    float gv = gbuf[0][s_upd][128 + j_upd];
                    float ov = gbuf[0][s_upd][192 + j_upd];
                    c_state = fmaf(fv, c_state, iv * gv);
                    h1buf[cur][s_upd][j_upd] = ov * fast_tanh(c_state);
                }
            } else {
                if (it >= 1) {
                    float iv = gbuf[1][s_upd][      j_upd];
                    float fv = gbuf[1][s_upd][ 64 + j_upd];
                    float gv = gbuf[1][s_upd][128 + j_upd];
                    float ov = gbuf[1][s_upd][192 + j_upd];
                    c_state = fmaf(fv, c_state, iv * gv);
                    float hv = ov * fast_tanh(c_state);
                    h2buf[prev][s_upd][j_upd] = hv;   // h2[it-1] -> buffer (it-1)&1
                    if (it == TT)
                        out[((size_t)blockIdx.x * 2 + s_upd) * HH + j_upd] = hv;
                }
            }
        }
        __syncthreads();
    }
}

extern "C" void kernel_launch(void* const* d_in, const int* in_sizes, int n_in,
                              void* d_out, int out_size, void* d_ws, size_t ws_size,
                              hipStream_t stream) {
    const float* x    = (const float*)d_in[0];
    const float* Wih0 = (const float*)d_in[1];
    const float* Whh0 = (const float*)d_in[2];
    const float* bih0 = (const float*)d_in[3];
    const float* bhh0 = (const float*)d_in[4];
    const float* Wih1 = (const float*)d_in[5];
    const float* Whh1 = (const float*)d_in[6];
    const float* bih1 = (const float*)d_in[7];
    const float* bhh1 = (const float*)d_in[8];
    float* out = (float*)d_out;

    // 512 sequences / 2 per block = 256 blocks (1 per CU), 512 threads (8 waves)
    lstm2_fused<<<256, 512, 0, stream>>>(x, Wih0, Whh0, bih0, bhh0,
                                         Wih1, Whh1, bih1, bhh1, out);
}

// Round 2
// 20216.756 us; speedup vs baseline: 1.4198x; 1.4198x over previous
//
#include <hip/hip_runtime.h>
#include <math.h>

// BiometricLSTM: 2-layer LSTM, B=512, T=2048, I=3, H=64, fp32. Output = final h of layer 2 (B,64).
//
// R2: kill the register spill from R1 (VGPR=128 but group1 held 128 weight floats ->
// scratch spill -> 29 GB HBM fetch, VALUBusy 7%). Every thread now holds <= 64+3
// weight floats. Layer 1's 128-long dot is split across two thread groups.
//
// 256 blocks x 768 threads (12 waves, 3/SIMD, VGPR cap ~170), 1 block/CU, one pass.
//   group0: threads [0,256)   layer-0 gate g (Whh0 row + Wih0 row + bias), both seqs
//   group1: threads [256,512) layer-1 gate g, ih half (Wih1 row) -> raw partial pA
//   group2: threads [512,768) layer-1 gate g, hh half (Whh1 row + bias) -> raw partial pB
// Layer-1 activation + state update happen on phase-2 update threads (reads pA+pB).
// Layers software-pipelined with 1-step lag; 2 barriers/step.

constexpr int TT = 2048;
constexpr int HH = 64;

__device__ __forceinline__ float fast_sigmoid(float x) {
    return 1.0f / (1.0f + __expf(-x));
}

// overflow-safe tanh: c can reach O(100s); exp(-2|x|) underflows harmlessly to 0 -> +/-1
__device__ __forceinline__ float fast_tanh(float x) {
    float ax = fabsf(x);
    float t  = __expf(-2.0f * ax);
    return copysignf((1.0f - t) / (1.0f + t), x);
}

__global__ __launch_bounds__(768, 3) void lstm2_fused(
    const float* __restrict__ x,
    const float* __restrict__ Wih0, const float* __restrict__ Whh0,
    const float* __restrict__ bih0, const float* __restrict__ bhh0,
    const float* __restrict__ Wih1, const float* __restrict__ Whh1,
    const float* __restrict__ bih1, const float* __restrict__ bhh1,
    float* __restrict__ out)
{
    __shared__ __align__(16) float xs[2 * TT * 3];      // 48 KB: x for both sequences
    __shared__ __align__(16) float h1buf[2][2][HH];     // [parity][seq][k]
    __shared__ __align__(16) float h2buf[2][2][HH];
    __shared__ __align__(16) float gbuf0[2][256];       // layer0 activated gates [seq][gate]
    __shared__ __align__(16) float pA[2][256];          // layer1 ih partials [seq][gate]
    __shared__ __align__(16) float pB[2][256];          // layer1 hh partials + bias

    const int tid   = threadIdx.x;
    const int group = tid >> 8;        // 0 | 1 | 2
    const int g     = tid & 255;

    // ---- preload x (coalesced, one-time): 2*2048*3 = 12288 floats = 3072 float4 ----
    {
        const float4* src = (const float4*)(x + (size_t)blockIdx.x * (2 * TT * 3));
        float4* dst = (float4*)xs;
        #pragma unroll
        for (int i = 0; i < 4; ++i) dst[tid + i * 768] = src[tid + i * 768];
    }
    // ---- zero h double-buffers (256 floats each) ----
    if (tid < 256)                      ((float*)h1buf)[tid] = 0.0f;
    else if (tid < 512)                 ((float*)h2buf)[tid - 256] = 0.0f;

    // ---- load this thread's 64 weight floats into registers ----
    float wreg[64];
    float wx0 = 0.f, wx1 = 0.f, wx2 = 0.f;
    float bias = 0.f;
    {
        const float* wsrc = (group == 0) ? (Whh0 + g * HH)
                          : (group == 1) ? (Wih1 + g * HH)
                                         : (Whh1 + g * HH);
        const float4* wr = (const float4*)wsrc;
        #pragma unroll
        for (int k4 = 0; k4 < 16; ++k4) {
            float4 v = wr[k4];
            wreg[4*k4+0] = v.x; wreg[4*k4+1] = v.y; wreg[4*k4+2] = v.z; wreg[4*k4+3] = v.w;
        }
        if (group == 0) {
            wx0 = Wih0[g*3+0]; wx1 = Wih0[g*3+1]; wx2 = Wih0[g*3+2];
            bias = bih0[g] + bhh0[g];
        } else if (group == 2) {
            bias = bih1[g] + bhh1[g];
        }
    }

    // phase-2 update identity (threads 0-127 of group0 -> layer0; 0-127 of group1 -> layer1)
    const int s_upd = (g >> 6) & 1;
    const int j_upd = g & 63;
    float c_state = 0.0f;

    __syncthreads();

    // iteration it: layer0 computes step it (it < T); layer1 computes step it-1 (it >= 1)
    for (int it = 0; it <= TT; ++it) {
        const int cur  = it & 1;
        const int prev = cur ^ 1;

        // ---------------- phase 1: gate dot-products (all groups concurrently) -------------
        if (group == 0) {
            if (it < TT) {
                float a0=0.f,b0=0.f,c0=0.f,d0=0.f, a1=0.f,b1=0.f,c1=0.f,d1=0.f;
                const float4* h0p = (const float4*)h1buf[prev][0];   // uniform broadcast
                const float4* h1p = (const float4*)h1buf[prev][1];
                #pragma unroll
                for (int k4 = 0; k4 < 16; ++k4) {
                    float4 hv0 = h0p[k4];
                    float4 hv1 = h1p[k4];
                    a0 = fmaf(wreg[4*k4+0], hv0.x, a0); b0 = fmaf(wreg[4*k4+1], hv0.y, b0);
                    c0 = fmaf(wreg[4*k4+2], hv0.z, c0); d0 = fmaf(wreg[4*k4+3], hv0.w, d0);
                    a1 = fmaf(wreg[4*k4+0], hv1.x, a1); b1 = fmaf(wreg[4*k4+1], hv1.y, b1);
                    c1 = fmaf(wreg[4*k4+2], hv1.z, c1); d1 = fmaf(wreg[4*k4+3], hv1.w, d1);
                }
                const int xb = it * 3;
                float gate0 = bias + (a0+b0) + (c0+d0)
                            + wx0*xs[xb] + wx1*xs[xb+1] + wx2*xs[xb+2];
                float gate1 = bias + (a1+b1) + (c1+d1)
                            + wx0*xs[6144+xb] + wx1*xs[6144+xb+1] + wx2*xs[6144+xb+2];
                if ((g >> 6) == 2) { gate0 = fast_tanh(gate0);    gate1 = fast_tanh(gate1); }
                else               { gate0 = fast_sigmoid(gate0); gate1 = fast_sigmoid(gate1); }
                gbuf0[0][g] = gate0;
                gbuf0[1][g] = gate1;
            }
        } else if (group == 1) {
            if (it >= 1) {
                // layer1 step it-1, ih half: Wih1[g] . h1[it-1] (= h1buf[prev])
                float a0=0.f,b0=0.f,c0=0.f,d0=0.f, a1=0.f,b1=0.f,c1=0.f,d1=0.f;
                const float4* i0p = (const float4*)h1buf[prev][0];
                const float4* i1p = (const float4*)h1buf[prev][1];
                #pragma unroll
                for (int k4 = 0; k4 < 16; ++k4) {
                    float4 hv0 = i0p[k4];
                    float4 hv1 = i1p[k4];
                    a0 = fmaf(wreg[4*k4+0], hv0.x, a0); b0 = fmaf(wreg[4*k4+1], hv0.y, b0);
                    c0 = fmaf(wreg[4*k4+2], hv0.z, c0); d0 = fmaf(wreg[4*k4+3], hv0.w, d0);
                    a1 = fmaf(wreg[4*k4+0], hv1.x, a1); b1 = fmaf(wreg[4*k4+1], hv1.y, b1);
                    c1 = fmaf(wreg[4*k4+2], hv1.z, c1); d1 = fmaf(wreg[4*k4+3], hv1.w, d1);
                }
                pA[0][g] = (a0+b0) + (c0+d0);
                pA[1][g] = (a1+b1) + (c1+d1);
            }
        } else {
            if (it >= 1) {
                // layer1 step it-1, hh half: Whh1[g] . h2[it-2] (= h2buf[cur]) + bias
                float a0=0.f,b0=0.f,c0=0.f,d0=0.f, a1=0.f,b1=0.f,c1=0.f,d1=0.f;
                const float4* r0p = (const float4*)h2buf[cur][0];
                const float4* r1p = (const float4*)h2buf[cur][1];
                #pragma unroll
                for (int k4 = 0; k4 < 16; ++k4) {
                    float4 hv0 = r0p[k4];
                    float4 hv1 = r1p[k4];
                    a0 = fmaf(wreg[4*k4+0], hv0.x, a0); b0 = fmaf(wreg[4*k4+1], hv0.y, b0);
                    c0 = fmaf(wreg[4*k4+2], hv0.z, c0); d0 = fmaf(wreg[4*k4+3], hv0.w, d0);
                    a1 = fmaf(wreg[4*k4+0], hv1.x, a1); b1 = fmaf(wreg[4*k4+1], hv1.y, b1);
                    c1 = fmaf(wreg[4*k4+2], hv1.z, c1); d1 = fmaf(wreg[4*k4+3], hv1.w, d1);
                }
                pB[0][g] = bias + (a0+b0) + (c0+d0);
                pB[1][g] = bias + (a1+b1) + (c1+d1);
            }
        }
        __syncthreads();

        // ---------------- phase 2: state updates (wave-aligned 128-thread slices) ----------
        if (g < 128) {
            if (group == 0) {
                if (it < TT) {
                    float iv = gbuf0[s_upd][      j_upd];
                    float fv = gbuf0[s_upd][ 64 + j_upd];
                    float gv = gbuf0[s_upd][128 + j_upd];
                    float ov = gbuf0[s_upd][192 + j_upd];
                    c_state = fmaf(fv, c_state, iv * gv);
                    h1buf[cur][s_upd][j_upd] = ov * fast_tanh(c_state);
                }
            } else if (group == 1) {
                if (it >= 1) {
                    float pre_i = pA[s_upd][      j_upd] + pB[s_upd][      j_upd];
                    float pre_f = pA[s_upd][ 64 + j_upd] + pB[s_upd][ 64 + j_upd];
                    float pre_g = pA[s_upd][128 + j_upd] + pB[s_upd][128 + j_upd];
                    float pre_o = pA[s_upd][192 + j_upd] + pB[s_upd][192 + j_upd];
                    float iv = fast_sigmoid(pre_i);
                    float fv = fast_sigmoid(pre_f);
                    float gv = fast_tanh(pre_g);
                    float ov = fast_sigmoid(pre_o);
                    c_state = fmaf(fv, c_state, iv * gv);
                    float hv = ov * fast_tanh(c_state);
                    h2buf[prev][s_upd][j_upd] = hv;   // h2[it-1] -> buffer (it-1)&1
                    if (it == TT)
                        out[((size_t)blockIdx.x * 2 + s_upd) * HH + j_upd] = hv;
                }
            }
        }
        __syncthreads();
    }
}

extern "C" void kernel_launch(void* const* d_in, const int* in_sizes, int n_in,
                              void* d_out, int out_size, void* d_ws, size_t ws_size,
                              hipStream_t stream) {
    const float* x    = (const float*)d_in[0];
    const float* Wih0 = (const float*)d_in[1];
    const float* Whh0 = (const float*)d_in[2];
    const float* bih0 = (const float*)d_in[3];
    const float* bhh0 = (const float*)d_in[4];
    const float* Wih1 = (const float*)d_in[5];
    const float* Whh1 = (const float*)d_in[6];
    const float* bih1 = (const float*)d_in[7];
    const float* bhh1 = (const float*)d_in[8];
    float* out = (float*)d_out;

    // 512 sequences / 2 per block = 256 blocks (1 per CU), 768 threads (12 waves)
    lstm2_fused<<<256, 768, 0, stream>>>(x, Wih0, Whh0, bih0, bhh0,
                                         Wih1, Whh1, bih1, bhh1, out);
}

// Round 3
// 20151.422 us; speedup vs baseline: 1.4244x; 1.0032x over previous
//
#include <hip/hip_runtime.h>
#include <math.h>

// BiometricLSTM: 2-layer LSTM, B=512, T=2048, I=3, H=64, fp32. Output = final h of layer 2 (B,64).
//
// R3: R2's spill root-caused — __launch_bounds__(768,3) made the backend compute
// waves/EU = min(3, LDS-limit=2 blocks) * 12 waves / 4 = 6 -> VGPR cap 512/6 = 84,
// below the ~100 the weight-resident design needs -> weights spilled to scratch
// (94 MB WRITE_SIZE one-time out, 2.9 GB FETCH_SIZE of re-reads). Grid is 256 =
// 1 block/CU by design, so declare (768,1): waves/EU = 3 -> cap 170 -> no spill.
//
// 256 blocks x 768 threads, 1 block/CU, one pass.
//   group0: threads [0,256)   layer-0 gate g (Whh0 row + Wih0 row + bias), both seqs
//   group1: threads [256,512) layer-1 gate g, ih half (Wih1 row) -> raw partial pA
//   group2: threads [512,768) layer-1 gate g, hh half (Whh1 row + bias) -> raw partial pB
// Layer-1 activation + state update happen on phase-2 update threads (reads pA+pB).
// Layers software-pipelined with 1-step lag; 2 barriers/step.

constexpr int TT = 2048;
constexpr int HH = 64;

__device__ __forceinline__ float fast_sigmoid(float x) {
    return 1.0f / (1.0f + __expf(-x));
}

// overflow-safe tanh: c can reach O(100s); exp(-2|x|) underflows harmlessly to 0 -> +/-1
__device__ __forceinline__ float fast_tanh(float x) {
    float ax = fabsf(x);
    float t  = __expf(-2.0f * ax);
    return copysignf((1.0f - t) / (1.0f + t), x);
}

__global__ __launch_bounds__(768, 1) void lstm2_fused(
    const float* __restrict__ x,
    const float* __restrict__ Wih0, const float* __restrict__ Whh0,
    const float* __restrict__ bih0, const float* __restrict__ bhh0,
    const float* __restrict__ Wih1, const float* __restrict__ Whh1,
    const float* __restrict__ bih1, const float* __restrict__ bhh1,
    float* __restrict__ out)
{
    __shared__ __align__(16) float xs[2 * TT * 3];      // 48 KB: x for both sequences
    __shared__ __align__(16) float h1buf[2][2][HH];     // [parity][seq][k]
    __shared__ __align__(16) float h2buf[2][2][HH];
    __shared__ __align__(16) float gbuf0[2][256];       // layer0 activated gates [seq][gate]
    __shared__ __align__(16) float pA[2][256];          // layer1 ih partials [seq][gate]
    __shared__ __align__(16) float pB[2][256];          // layer1 hh partials + bias

    const int tid   = threadIdx.x;
    const int group = tid >> 8;        // 0 | 1 | 2
    const int g     = tid & 255;

    // ---- preload x (coalesced, one-time): 2*2048*3 = 12288 floats = 3072 float4 ----
    {
        const float4* src = (const float4*)(x + (size_t)blockIdx.x * (2 * TT * 3));
        float4* dst = (float4*)xs;
        #pragma unroll
        for (int i = 0; i < 4; ++i) dst[tid + i * 768] = src[tid + i * 768];
    }
    // ---- zero h double-buffers (256 floats each) ----
    if (tid < 256)                      ((float*)h1buf)[tid] = 0.0f;
    else if (tid < 512)                 ((float*)h2buf)[tid - 256] = 0.0f;

    // ---- load this thread's 64 weight floats into registers ----
    float wreg[64];
    float wx0 = 0.f, wx1 = 0.f, wx2 = 0.f;
    float bias = 0.f;
    {
        const float* wsrc = (group == 0) ? (Whh0 + g * HH)
                          : (group == 1) ? (Wih1 + g * HH)
                                         : (Whh1 + g * HH);
        const float4* wr = (const float4*)wsrc;
        #pragma unroll
        for (int k4 = 0; k4 < 16; ++k4) {
            float4 v = wr[k4];
            wreg[4*k4+0] = v.x; wreg[4*k4+1] = v.y; wreg[4*k4+2] = v.z; wreg[4*k4+3] = v.w;
        }
        if (group == 0) {
            wx0 = Wih0[g*3+0]; wx1 = Wih0[g*3+1]; wx2 = Wih0[g*3+2];
            bias = bih0[g] + bhh0[g];
        } else if (group == 2) {
            bias = bih1[g] + bhh1[g];
        }
    }

    // phase-2 update identity (threads 0-127 of group0 -> layer0; 0-127 of group1 -> layer1)
    const int s_upd = (g >> 6) & 1;
    const int j_upd = g & 63;
    float c_state = 0.0f;

    __syncthreads();

    // iteration it: layer0 computes step it (it < T); layer1 computes step it-1 (it >= 1)
    for (int it = 0; it <= TT; ++it) {
        const int cur  = it & 1;
        const int prev = cur ^ 1;

        // ---------------- phase 1: gate dot-products (all groups concurrently) -------------
        if (group == 0) {
            if (it < TT) {
                float a0=0.f,b0=0.f,c0=0.f,d0=0.f, a1=0.f,b1=0.f,c1=0.f,d1=0.f;
                const float4* h0p = (const float4*)h1buf[prev][0];   // uniform broadcast
                const float4* h1p = (const float4*)h1buf[prev][1];
                #pragma unroll
                for (int k4 = 0; k4 < 16; ++k4) {
                    float4 hv0 = h0p[k4];
                    float4 hv1 = h1p[k4];
                    a0 = fmaf(wreg[4*k4+0], hv0.x, a0); b0 = fmaf(wreg[4*k4+1], hv0.y, b0);
                    c0 = fmaf(wreg[4*k4+2], hv0.z, c0); d0 = fmaf(wreg[4*k4+3], hv0.w, d0);
                    a1 = fmaf(wreg[4*k4+0], hv1.x, a1); b1 = fmaf(wreg[4*k4+1], hv1.y, b1);
                    c1 = fmaf(wreg[4*k4+2], hv1.z, c1); d1 = fmaf(wreg[4*k4+3], hv1.w, d1);
                }
                const int xb = it * 3;
                float gate0 = bias + (a0+b0) + (c0+d0)
                            + wx0*xs[xb] + wx1*xs[xb+1] + wx2*xs[xb+2];
                float gate1 = bias + (a1+b1) + (c1+d1)
                            + wx0*xs[6144+xb] + wx1*xs[6144+xb+1] + wx2*xs[6144+xb+2];
                if ((g >> 6) == 2) { gate0 = fast_tanh(gate0);    gate1 = fast_tanh(gate1); }
                else               { gate0 = fast_sigmoid(gate0); gate1 = fast_sigmoid(gate1); }
                gbuf0[0][g] = gate0;
                gbuf0[1][g] = gate1;
            }
        } else if (group == 1) {
            if (it >= 1) {
                // layer1 step it-1, ih half: Wih1[g] . h1[it-1] (= h1buf[prev])
                float a0=0.f,b0=0.f,c0=0.f,d0=0.f, a1=0.f,b1=0.f,c1=0.f,d1=0.f;
                const float4* i0p = (const float4*)h1buf[prev][0];
                const float4* i1p = (const float4*)h1buf[prev][1];
                #pragma unroll
                for (int k4 = 0; k4 < 16; ++k4) {
                    float4 hv0 = i0p[k4];
                    float4 hv1 = i1p[k4];
                    a0 = fmaf(wreg[4*k4+0], hv0.x, a0); b0 = fmaf(wreg[4*k4+1], hv0.y, b0);
                    c0 = fmaf(wreg[4*k4+2], hv0.z, c0); d0 = fmaf(wreg[4*k4+3], hv0.w, d0);
                    a1 = fmaf(wreg[4*k4+0], hv1.x, a1); b1 = fmaf(wreg[4*k4+1], hv1.y, b1);
                    c1 = fmaf(wreg[4*k4+2], hv1.z, c1); d1 = fmaf(wreg[4*k4+3], hv1.w, d1);
                }
                pA[0][g] = (a0+b0) + (c0+d0);
                pA[1][g] = (a1+b1) + (c1+d1);
            }
        } else {
            if (it >= 1) {
                // layer1 step it-1, hh half: Whh1[g] . h2[it-2] (= h2buf[cur]) + bias
                float a0=0.f,b0=0.f,c0=0.f,d0=0.f, a1=0.f,b1=0.f,c1=0.f,d1=0.f;
                const float4* r0p = (const float4*)h2buf[cur][0];
                const float4* r1p = (const float4*)h2buf[cur][1];
                #pragma unroll
                for (int k4 = 0; k4 < 16; ++k4) {
                    float4 hv0 = r0p[k4];
                    float4 hv1 = r1p[k4];
                    a0 = fmaf(wreg[4*k4+0], hv0.x, a0); b0 = fmaf(wreg[4*k4+1], hv0.y, b0);
                    c0 = fmaf(wreg[4*k4+2], hv0.z, c0); d0 = fmaf(wreg[4*k4+3], hv0.w, d0);
                    a1 = fmaf(wreg[4*k4+0], hv1.x, a1); b1 = fmaf(wreg[4*k4+1], hv1.y, b1);
                    c1 = fmaf(wreg[4*k4+2], hv1.z, c1); d1 = fmaf(wreg[4*k4+3], hv1.w, d1);
                }
                pB[0][g] = bias + (a0+b0) + (c0+d0);
                pB[1][g] = bias + (a1+b1) + (c1+d1);
            }
        }
        __syncthreads();

        // ---------------- phase 2: state updates (wave-aligned 128-thread slices) ----------
        if (g < 128) {
            if (group == 0) {
                if (it < TT) {
                    float iv = gbuf0[s_upd][      j_upd];
                    float fv = gbuf0[s_upd][ 64 + j_upd];
                    float gv = gbuf0[s_upd][128 + j_upd];
                    float ov = gbuf0[s_upd][192 + j_upd];
                    c_state = fmaf(fv, c_state, iv * gv);
                    h1buf[cur][s_upd][j_upd] = ov * fast_tanh(c_state);
                }
            } else if (group == 1) {
                if (it >= 1) {
                    float pre_i = pA[s_upd][      j_upd] + pB[s_upd][      j_upd];
                    float pre_f = pA[s_upd][ 64 + j_upd] + pB[s_upd][ 64 + j_upd];
                    float pre_g = pA[s_upd][128 + j_upd] + pB[s_upd][128 + j_upd];
                    float pre_o = pA[s_upd][192 + j_upd] + pB[s_upd][192 + j_upd];
                    float iv = fast_sigmoid(pre_i);
                    float fv = fast_sigmoid(pre_f);
                    float gv = fast_tanh(pre_g);
                    float ov = fast_sigmoid(pre_o);
                    c_state = fmaf(fv, c_state, iv * gv);
                    float hv = ov * fast_tanh(c_state);
                    h2buf[prev][s_upd][j_upd] = hv;   // h2[it-1] -> buffer (it-1)&1
                    if (it == TT)
                        out[((size_t)blockIdx.x * 2 + s_upd) * HH + j_upd] = hv;
                }
            }
        }
        __syncthreads();
    }
}

extern "C" void kernel_launch(void* const* d_in, const int* in_sizes, int n_in,
                              void* d_out, int out_size, void* d_ws, size_t ws_size,
                              hipStream_t stream) {
    const float* x    = (const float*)d_in[0];
    const float* Wih0 = (const float*)d_in[1];
    const float* Whh0 = (const float*)d_in[2];
    const float* bih0 = (const float*)d_in[3];
    const float* bhh0 = (const float*)d_in[4];
    const float* Wih1 = (const float*)d_in[5];
    const float* Whh1 = (const float*)d_in[6];
    const float* bih1 = (const float*)d_in[7];
    const float* bhh1 = (const float*)d_in[8];
    float* out = (float*)d_out;

    // 512 sequences / 2 per block = 256 blocks (1 per CU), 768 threads (12 waves)
    lstm2_fused<<<256, 768, 0, stream>>>(x, Wih0, Whh0, bih0, bhh0,
                                         Wih1, Whh1, bih1, bhh1, out);
}

// Round 4
// 14501.700 us; speedup vs baseline: 1.9794x; 1.3896x over previous
//
#include <hip/hip_runtime.h>
#include <math.h>

// BiometricLSTM: 2-layer LSTM, B=512, T=2048, I=3, H=64, fp32. Output = final h of layer 2 (B,64).
//
// R4: R2/R3 both got VGPR_Count=84 regardless of __launch_bounds__ second arg ->
// the backend's register budget came from the LDS-derived occupancy default
// (57 KB -> 2 blocks/CU -> 6 waves/EU -> cap 512/6 = 84), below the ~110 the
// weight-resident design needs -> weight spill -> 94 MB scratch writes + 2.9 GB
// scratch re-reads, VALUBusy 9%. Fix (two redundant mechanisms):
//   1. amdgpu_waves_per_eu(3,3) attribute -> cap 512/3 ~= 168.
//   2. pad LDS to 82944 B (> 80 KiB) so only 1 block/CU fits by LDS -> the
//      LDS-derived default also becomes 3 waves/EU. Grid is 1 block/CU anyway.
//
// 256 blocks x 768 threads, 1 block/CU, one pass.
//   group0: threads [0,256)   layer-0 gate g (Whh0 row + Wih0 row + bias), both seqs
//   group1: threads [256,512) layer-1 gate g, ih half (Wih1 row) -> raw partial pA
//   group2: threads [512,768) layer-1 gate g, hh half (Whh1 row + bias) -> raw partial pB
// Layer-1 activation + state update happen on phase-2 update threads (reads pA+pB).
// Layers software-pipelined with 1-step lag; 2 barriers/step.

constexpr int TT = 2048;
constexpr int HH = 64;

__device__ __forceinline__ float fast_sigmoid(float x) {
    return 1.0f / (1.0f + __expf(-x));
}

// overflow-safe tanh: c can reach O(100s); exp(-2|x|) underflows harmlessly to 0 -> +/-1
__device__ __forceinline__ float fast_tanh(float x) {
    float ax = fabsf(x);
    float t  = __expf(-2.0f * ax);
    return copysignf((1.0f - t) / (1.0f + t), x);
}

__global__ __attribute__((amdgpu_flat_work_group_size(768, 768), amdgpu_waves_per_eu(3, 3)))
void lstm2_fused(
    const float* __restrict__ x,
    const float* __restrict__ Wih0, const float* __restrict__ Whh0,
    const float* __restrict__ bih0, const float* __restrict__ bhh0,
    const float* __restrict__ Wih1, const float* __restrict__ Whh1,
    const float* __restrict__ bih1, const float* __restrict__ bhh1,
    float* __restrict__ out)
{
    // 2*TT*3 = 12288 floats used; +6400 floats of padding pushes LDS/block to
    // 82944 B > 80 KiB so at most 1 block/CU fits -> backend targets 3 waves/EU
    // -> VGPR cap ~168 (no spill). The pad lives inside a used array so it
    // cannot be eliminated.
    __shared__ __align__(16) float xs[2 * TT * 3 + 6400];
    __shared__ __align__(16) float h1buf[2][2][HH];     // [parity][seq][k]
    __shared__ __align__(16) float h2buf[2][2][HH];
    __shared__ __align__(16) float gbuf0[2][256];       // layer0 activated gates [seq][gate]
    __shared__ __align__(16) float pA[2][256];          // layer1 ih partials [seq][gate]
    __shared__ __align__(16) float pB[2][256];          // layer1 hh partials + bias

    const int tid   = threadIdx.x;
    const int group = tid >> 8;        // 0 | 1 | 2
    const int g     = tid & 255;

    // ---- preload x (coalesced, one-time): 2*2048*3 = 12288 floats = 3072 float4 ----
    {
        const float4* src = (const float4*)(x + (size_t)blockIdx.x * (2 * TT * 3));
        float4* dst = (float4*)xs;
        #pragma unroll
        for (int i = 0; i < 4; ++i) dst[tid + i * 768] = src[tid + i * 768];
    }
    // ---- zero h double-buffers (256 floats each) ----
    if (tid < 256)                      ((float*)h1buf)[tid] = 0.0f;
    else if (tid < 512)                 ((float*)h2buf)[tid - 256] = 0.0f;

    // ---- load this thread's 64 weight floats into registers ----
    float wreg[64];
    float wx0 = 0.f, wx1 = 0.f, wx2 = 0.f;
    float bias = 0.f;
    {
        const float* wsrc = (group == 0) ? (Whh0 + g * HH)
                          : (group == 1) ? (Wih1 + g * HH)
                                         : (Whh1 + g * HH);
        const float4* wr = (const float4*)wsrc;
        #pragma unroll
        for (int k4 = 0; k4 < 16; ++k4) {
            float4 v = wr[k4];
            wreg[4*k4+0] = v.x; wreg[4*k4+1] = v.y; wreg[4*k4+2] = v.z; wreg[4*k4+3] = v.w;
        }
        if (group == 0) {
            wx0 = Wih0[g*3+0]; wx1 = Wih0[g*3+1]; wx2 = Wih0[g*3+2];
            bias = bih0[g] + bhh0[g];
        } else if (group == 2) {
            bias = bih1[g] + bhh1[g];
        }
    }

    // phase-2 update identity (threads 0-127 of group0 -> layer0; 0-127 of group1 -> layer1)
    const int s_upd = (g >> 6) & 1;
    const int j_upd = g & 63;
    float c_state = 0.0f;

    __syncthreads();

    // iteration it: layer0 computes step it (it < T); layer1 computes step it-1 (it >= 1)
    for (int it = 0; it <= TT; ++it) {
        const int cur  = it & 1;
        const int prev = cur ^ 1;

        // ---------------- phase 1: gate dot-products (all groups concurrently) -------------
        if (group == 0) {
            if (it < TT) {
                float a0=0.f,b0=0.f,c0=0.f,d0=0.f, a1=0.f,b1=0.f,c1=0.f,d1=0.f;
                const float4* h0p = (const float4*)h1buf[prev][0];   // uniform broadcast
                const float4* h1p = (const float4*)h1buf[prev][1];
                #pragma unroll
                for (int k4 = 0; k4 < 16; ++k4) {
                    float4 hv0 = h0p[k4];
                    float4 hv1 = h1p[k4];
                    a0 = fmaf(wreg[4*k4+0], hv0.x, a0); b0 = fmaf(wreg[4*k4+1], hv0.y, b0);
                    c0 = fmaf(wreg[4*k4+2], hv0.z, c0); d0 = fmaf(wreg[4*k4+3], hv0.w, d0);
                    a1 = fmaf(wreg[4*k4+0], hv1.x, a1); b1 = fmaf(wreg[4*k4+1], hv1.y, b1);
                    c1 = fmaf(wreg[4*k4+2], hv1.z, c1); d1 = fmaf(wreg[4*k4+3], hv1.w, d1);
                }
                const int xb = it * 3;
                float gate0 = bias + (a0+b0) + (c0+d0)
                            + wx0*xs[xb] + wx1*xs[xb+1] + wx2*xs[xb+2];
                float gate1 = bias + (a1+b1) + (c1+d1)
                            + wx0*xs[6144+xb] + wx1*xs[6144+xb+1] + wx2*xs[6144+xb+2];
                if ((g >> 6) == 2) { gate0 = fast_tanh(gate0);    gate1 = fast_tanh(gate1); }
                else               { gate0 = fast_sigmoid(gate0); gate1 = fast_sigmoid(gate1); }
                gbuf0[0][g] = gate0;
                gbuf0[1][g] = gate1;
            }
        } else if (group == 1) {
            if (it >= 1) {
                // layer1 step it-1, ih half: Wih1[g] . h1[it-1] (= h1buf[prev])
                float a0=0.f,b0=0.f,c0=0.f,d0=0.f, a1=0.f,b1=0.f,c1=0.f,d1=0.f;
                const float4* i0p = (const float4*)h1buf[prev][0];
                const float4* i1p = (const float4*)h1buf[prev][1];
                #pragma unroll
                for (int k4 = 0; k4 < 16; ++k4) {
                    float4 hv0 = i0p[k4];
                    float4 hv1 = i1p[k4];
                    a0 = fmaf(wreg[4*k4+0], hv0.x, a0); b0 = fmaf(wreg[4*k4+1], hv0.y, b0);
                    c0 = fmaf(wreg[4*k4+2], hv0.z, c0); d0 = fmaf(wreg[4*k4+3], hv0.w, d0);
                    a1 = fmaf(wreg[4*k4+0], hv1.x, a1); b1 = fmaf(wreg[4*k4+1], hv1.y, b1);
                    c1 = fmaf(wreg[4*k4+2], hv1.z, c1); d1 = fmaf(wreg[4*k4+3], hv1.w, d1);
                }
                pA[0][g] = (a0+b0) + (c0+d0);
                pA[1][g] = (a1+b1) + (c1+d1);
            }
        } else {
            if (it >= 1) {
                // layer1 step it-1, hh half: Whh1[g] . h2[it-2] (= h2buf[cur]) + bias
                float a0=0.f,b0=0.f,c0=0.f,d0=0.f, a1=0.f,b1=0.f,c1=0.f,d1=0.f;
                const float4* r0p = (const float4*)h2buf[cur][0];
                const float4* r1p = (const float4*)h2buf[cur][1];
                #pragma unroll
                for (int k4 = 0; k4 < 16; ++k4) {
                    float4 hv0 = r0p[k4];
                    float4 hv1 = r1p[k4];
                    a0 = fmaf(wreg[4*k4+0], hv0.x, a0); b0 = fmaf(wreg[4*k4+1], hv0.y, b0);
                    c0 = fmaf(wreg[4*k4+2], hv0.z, c0); d0 = fmaf(wreg[4*k4+3], hv0.w, d0);
                    a1 = fmaf(wreg[4*k4+0], hv1.x, a1); b1 = fmaf(wreg[4*k4+1], hv1.y, b1);
                    c1 = fmaf(wreg[4*k4+2], hv1.z, c1); d1 = fmaf(wreg[4*k4+3], hv1.w, d1);
                }
                pB[0][g] = bias + (a0+b0) + (c0+d0);
                pB[1][g] = bias + (a1+b1) + (c1+d1);
            }
        }
        __syncthreads();

        // ---------------- phase 2: state updates (wave-aligned 128-thread slices) ----------
        if (g < 128) {
            if (group == 0) {
                if (it < TT) {
                    float iv = gbuf0[s_upd][      j_upd];
                    float fv = gbuf0[s_upd][ 64 + j_upd];
                    float gv = gbuf0[s_upd][128 + j_upd];
                    float ov = gbuf0[s_upd][192 + j_upd];
                    c_state = fmaf(fv, c_state, iv * gv);
                    h1buf[cur][s_upd][j_upd] = ov * fast_tanh(c_state);
                }
            } else if (group == 1) {
                if (it >= 1) {
                    float pre_i = pA[s_upd][      j_upd] + pB[s_upd][      j_upd];
                    float pre_f = pA[s_upd][ 64 + j_upd] + pB[s_upd][ 64 + j_upd];
                    float pre_g = pA[s_upd][128 + j_upd] + pB[s_upd][128 + j_upd];
                    float pre_o = pA[s_upd][192 + j_upd] + pB[s_upd][192 + j_upd];
                    float iv = fast_sigmoid(pre_i);
                    float fv = fast_sigmoid(pre_f);
                    float gv = fast_tanh(pre_g);
                    float ov = fast_sigmoid(pre_o);
                    c_state = fmaf(fv, c_state, iv * gv);
                    float hv = ov * fast_tanh(c_state);
                    h2buf[prev][s_upd][j_upd] = hv;   // h2[it-1] -> buffer (it-1)&1
                    if (it == TT)
                        out[((size_t)blockIdx.x * 2 + s_upd) * HH + j_upd] = hv;
                }
            }
        }
        __syncthreads();
    }
}

extern "C" void kernel_launch(void* const* d_in, const int* in_sizes, int n_in,
                              void* d_out, int out_size, void* d_ws, size_t ws_size,
                              hipStream_t stream) {
    const float* x    = (const float*)d_in[0];
    const float* Wih0 = (const float*)d_in[1];
    const float* Whh0 = (const float*)d_in[2];
    const float* bih0 = (const float*)d_in[3];
    const float* bhh0 = (const float*)d_in[4];
    const float* Wih1 = (const float*)d_in[5];
    const float* Whh1 = (const float*)d_in[6];
    const float* bih1 = (const float*)d_in[7];
    const float* bhh1 = (const float*)d_in[8];
    float* out = (float*)d_out;

    // 512 sequences / 2 per block = 256 blocks (1 per CU), 768 threads (12 waves)
    lstm2_fused<<<256, 768, 0, stream>>>(x, Wih0, Whh0, bih0, bhh0,
                                         Wih1, Whh1, bih1, bhh1, out);
}

// Round 5
// 5036.435 us; speedup vs baseline: 5.6993x; 2.8794x over previous
//
#include <hip/hip_runtime.h>
#include <math.h>

// BiometricLSTM: 2-layer LSTM, B=512, T=2048, I=3, H=64, fp32. Output = final h of layer 2 (B,64).
//
// R5: R2-R4 showed the register allocator budgets VGPRs for 2 resident blocks no
// matter what __launch_bounds__/amdgpu_waves_per_eu say: budget = 1024/waves_per_block
// (R1: 8 waves->128, R2-4: 12 waves->84; all observed). The 64-weight/thread design
// needs ~100 -> permanent spill. Fix by restructure: 256 threads/block (4 waves) ->
// budget 256. Thread j owns gate j of BOTH layers (195 weight floats, demand ~235).
// Bonus: L0 and L1-ih dots share the same h1[prev] loads -> half the LDS broadcasts.
//
// 256 blocks x 256 threads, 1 block/CU, 2 seqs/block.
//   phase 1 (all threads): full gate pre-acts for L0 step it and L1 step it-1,
//     activation applied in-phase (gate class = wave index, wave-uniform branch).
//   phase 2: thread t = (layer, seq, j) state update; c_state in registers.
// Layers software-pipelined with 1-step lag; 2 barriers/step.

constexpr int TT = 2048;

__device__ __forceinline__ float fast_sigmoid(float x) {
    return 1.0f / (1.0f + __expf(-x));
}

// overflow-safe tanh: c can reach O(100s); exp(-2|x|) underflows harmlessly to 0 -> +/-1
__device__ __forceinline__ float fast_tanh(float x) {
    float ax = fabsf(x);
    float t  = __expf(-2.0f * ax);
    return copysignf((1.0f - t) / (1.0f + t), x);
}

__global__ __launch_bounds__(256) void lstm2_fused(
    const float* __restrict__ x,
    const float* __restrict__ Wih0, const float* __restrict__ Whh0,
    const float* __restrict__ bih0, const float* __restrict__ bhh0,
    const float* __restrict__ Wih1, const float* __restrict__ Whh1,
    const float* __restrict__ bih1, const float* __restrict__ bhh1,
    float* __restrict__ out)
{
    // +4 pad: the unconditional phase-1 compute at it==TT reads xs[2*6144+2]
    __shared__ __align__(16) float xs[2 * TT * 3 + 4];   // ~48 KB
    __shared__ __align__(16) float h1buf[2][2][64];      // [parity][seq][k]
    __shared__ __align__(16) float h2buf[2][2][64];
    __shared__ __align__(16) float gbuf[2][2][256];      // [layer][seq][gate], activated

    const int j = threadIdx.x;            // gate index 0..255

    // ---- preload x (coalesced): 2*2048*3 = 12288 floats = 3072 float4, 12/thread ----
    {
        const float4* src = (const float4*)(x + (size_t)blockIdx.x * (2 * TT * 3));
        float4* dst = (float4*)xs;
        #pragma unroll
        for (int i = 0; i < 12; ++i) dst[j + i * 256] = src[j + i * 256];
    }
    // ---- zero h double-buffers (256 floats each) ----
    ((float*)h1buf)[j] = 0.0f;
    ((float*)h2buf)[j] = 0.0f;

    // ---- thread j's weights: gate j of both layers (195 floats, registers) ----
    float wA[64], wB[64], wC[64];   // Whh0 row j | Wih1 row j | Whh1 row j
    {
        const float4* a = (const float4*)(Whh0 + j * 64);
        const float4* b = (const float4*)(Wih1 + j * 64);
        const float4* c = (const float4*)(Whh1 + j * 64);
        #pragma unroll
        for (int k = 0; k < 16; ++k) {
            float4 va = a[k];
            wA[4*k+0] = va.x; wA[4*k+1] = va.y; wA[4*k+2] = va.z; wA[4*k+3] = va.w;
            float4 vb = b[k];
            wB[4*k+0] = vb.x; wB[4*k+1] = vb.y; wB[4*k+2] = vb.z; wB[4*k+3] = vb.w;
            float4 vc = c[k];
            wC[4*k+0] = vc.x; wC[4*k+1] = vc.y; wC[4*k+2] = vc.z; wC[4*k+3] = vc.w;
        }
    }
    const float wx0 = Wih0[j*3+0], wx1 = Wih0[j*3+1], wx2 = Wih0[j*3+2];
    const float bias0 = bih0[j] + bhh0[j];
    const float bias1 = bih1[j] + bhh1[j];

    const int cls = j >> 6;               // 0:i 1:f 2:g 3:o  (== wave index, uniform)
    // phase-2 identity: thread j updates (layer uL, seq us, elem uj)
    const int uL = j >> 7, us = (j >> 6) & 1, uj = j & 63;
    float c_state = 0.0f;

    __syncthreads();

    // iteration it: L0 computes step it (valid it<TT); L1 computes step it-1 (valid it>=1).
    // Edge iterations compute garbage unconditionally (inputs are zeroed buffers, in-bounds);
    // only the state updates / stores are guarded.
    for (int it = 0; it <= TT; ++it) {
        const int cur  = it & 1;
        const int prev = cur ^ 1;

        // ---------------- phase 1: all gate dot-products ----------------
        const float4* h1p0 = (const float4*)h1buf[prev][0];   // h1[it-1], seq0 (broadcast)
        const float4* h1p1 = (const float4*)h1buf[prev][1];
        const float4* h2p0 = (const float4*)h2buf[cur][0];    // h2[it-2], seq0
        const float4* h2p1 = (const float4*)h2buf[cur][1];

        float A0a=0.f,A0b=0.f,A1a=0.f,A1b=0.f;   // L0 (Whh0.h1) seq0/seq1
        float I0a=0.f,I0b=0.f,I1a=0.f,I1b=0.f;   // L1 ih (Wih1.h1)
        float H0a=0.f,H0b=0.f,H1a=0.f,H1b=0.f;   // L1 hh (Whh1.h2)
        #pragma unroll
        for (int k = 0; k < 16; ++k) {
            float4 p = h1p0[k];
            float4 q = h1p1[k];
            float4 r = h2p0[k];
            float4 u = h2p1[k];
            A0a = fmaf(wA[4*k+0], p.x, A0a); A0b = fmaf(wA[4*k+1], p.y, A0b);
            A0a = fmaf(wA[4*k+2], p.z, A0a); A0b = fmaf(wA[4*k+3], p.w, A0b);
            A1a = fmaf(wA[4*k+0], q.x, A1a); A1b = fmaf(wA[4*k+1], q.y, A1b);
            A1a = fmaf(wA[4*k+2], q.z, A1a); A1b = fmaf(wA[4*k+3], q.w, A1b);
            I0a = fmaf(wB[4*k+0], p.x, I0a); I0b = fmaf(wB[4*k+1], p.y, I0b);
            I0a = fmaf(wB[4*k+2], p.z, I0a); I0b = fmaf(wB[4*k+3], p.w, I0b);
            I1a = fmaf(wB[4*k+0], q.x, I1a); I1b = fmaf(wB[4*k+1], q.y, I1b);
            I1a = fmaf(wB[4*k+2], q.z, I1a); I1b = fmaf(wB[4*k+3], q.w, I1b);
            H0a = fmaf(wC[4*k+0], r.x, H0a); H0b = fmaf(wC[4*k+1], r.y, H0b);
            H0a = fmaf(wC[4*k+2], r.z, H0a); H0b = fmaf(wC[4*k+3], r.w, H0b);
            H1a = fmaf(wC[4*k+0], u.x, H1a); H1b = fmaf(wC[4*k+1], u.y, H1b);
            H1a = fmaf(wC[4*k+2], u.z, H1a); H1b = fmaf(wC[4*k+3], u.w, H1b);
        }
        const int xb = it * 3;
        float g00 = bias0 + (A0a + A0b) + wx0*xs[xb]      + wx1*xs[xb+1]      + wx2*xs[xb+2];
        float g01 = bias0 + (A1a + A1b) + wx0*xs[6144+xb] + wx1*xs[6144+xb+1] + wx2*xs[6144+xb+2];
        float g10 = bias1 + (I0a + I0b) + (H0a + H0b);
        float g11 = bias1 + (I1a + I1b) + (H1a + H1b);
        if (cls == 2) {                       // g-gate wave: tanh
            g00 = fast_tanh(g00);    g01 = fast_tanh(g01);
            g10 = fast_tanh(g10);    g11 = fast_tanh(g11);
        } else {                              // i/f/o waves: sigmoid
            g00 = fast_sigmoid(g00); g01 = fast_sigmoid(g01);
            g10 = fast_sigmoid(g10); g11 = fast_sigmoid(g11);
        }
        gbuf[0][0][j] = g00;
        gbuf[0][1][j] = g01;
        gbuf[1][0][j] = g10;
        gbuf[1][1][j] = g11;
        __syncthreads();

        // ---------------- phase 2: state updates (1 thread per (layer,seq,j)) --------------
        if (uL == 0) {
            if (it < TT) {
                float iv = gbuf[0][us][      uj];
                float fv = gbuf[0][us][ 64 + uj];
                float gv = gbuf[0][us][128 + uj];
                float ov = gbuf[0][us][192 + uj];
                c_state = fmaf(fv, c_state, iv * gv);
                h1buf[cur][us][uj] = ov * fast_tanh(c_state);   // h1[it]
            }
        } else {
            if (it >= 1) {
                float iv = gbuf[1][us][      uj];
                float fv = gbuf[1][us][ 64 + uj];
                float gv = gbuf[1][us][128 + uj];
                float ov = gbuf[1][us][192 + uj];
                c_state = fmaf(fv, c_state, iv * gv);
                float hv = ov * fast_tanh(c_state);
                h2buf[prev][us][uj] = hv;                        // h2[it-1]
                if (it == TT)
                    out[((size_t)blockIdx.x * 2 + us) * 64 + uj] = hv;
            }
        }
        __syncthreads();
    }
}

extern "C" void kernel_launch(void* const* d_in, const int* in_sizes, int n_in,
                              void* d_out, int out_size, void* d_ws, size_t ws_size,
                              hipStream_t stream) {
    const float* x    = (const float*)d_in[0];
    const float* Wih0 = (const float*)d_in[1];
    const float* Whh0 = (const float*)d_in[2];
    const float* bih0 = (const float*)d_in[3];
    const float* bhh0 = (const float*)d_in[4];
    const float* Wih1 = (const float*)d_in[5];
    const float* Whh1 = (const float*)d_in[6];
    const float* bih1 = (const float*)d_in[7];
    const float* bhh1 = (const float*)d_in[8];
    float* out = (float*)d_out;

    // 512 sequences / 2 per block = 256 blocks (1 per CU), 256 threads (4 waves)
    lstm2_fused<<<256, 256, 0, stream>>>(x, Wih0, Whh0, bih0, bhh0,
                                         Wih1, Whh1, bih1, bhh1, out);
}

// Round 6
// 2256.364 us; speedup vs baseline: 12.7215x; 2.2321x over previous
//
#include <hip/hip_runtime.h>
#include <math.h>

// BiometricLSTM: 2-layer LSTM, B=512, T=2048, I=3, H=64, fp32. Output = final h of layer 2 (B,64).
//
// R6: R5 (256 blocks x 2 seq, 4 waves, VGPR=256, no spill) ran 5.04 ms =
// ~5900 cyc/iter vs ~770 cyc static VALU floor -- latency-bound at 1 wave/SIMD
// (exposed ds_read latency, barrier drains, serial phase-2 chains).
// Restructure: 512 blocks x 1 seq each -> 2 blocks/CU -> 2 waves/SIMD. Totals
// per CU conserved; co-resident blocks' phases interleave (barriers are
// per-block), hiding LDS latency with the other block's FMAs.
// Per-thread: gate j of both layers, 192 weight floats in VGPRs (budget
// 1024/4 waves = 256, observed law R1-R5). x packed stride-4 -> 1 b128/iter.
//
//   phase 1 (all 256 threads): L0 gate j (step it) + L1 gate j (step it-1),
//     activation in-phase (gate class == wave index, uniform branch).
//   phase 2 (threads 0-127): wave0 = L0 state update, wave1 = L1 state update;
//     c_state in registers. 2 barriers/iter. Layers pipelined with 1-step lag.

constexpr int TT = 2048;

__device__ __forceinline__ float fast_sigmoid(float x) {
    return 1.0f / (1.0f + __expf(-x));
}

// overflow-safe tanh: c can reach O(100s); exp(-2|x|) underflows harmlessly to 0 -> +/-1
__device__ __forceinline__ float fast_tanh(float x) {
    float ax = fabsf(x);
    float t  = __expf(-2.0f * ax);
    return copysignf((1.0f - t) / (1.0f + t), x);
}

__global__ __launch_bounds__(256) void lstm2_fused(
    const float* __restrict__ x,
    const float* __restrict__ Wih0, const float* __restrict__ Whh0,
    const float* __restrict__ bih0, const float* __restrict__ bhh0,
    const float* __restrict__ Wih1, const float* __restrict__ Whh1,
    const float* __restrict__ bih1, const float* __restrict__ bhh1,
    float* __restrict__ out)
{
    // x for this block's single sequence, padded to stride 4 so the per-iter
    // read is one ds_read_b128. +4 tail: the unconditional it==TT read.
    __shared__ __align__(16) float xs4[TT * 4 + 4];     // 32 KB
    __shared__ __align__(16) float h1buf[2][64];        // [parity][k]
    __shared__ __align__(16) float h2buf[2][64];
    __shared__ __align__(16) float gbuf[2][256];        // [layer][gate], activated

    const int j = threadIdx.x;            // gate index 0..255

    // ---- preload x: global (T,3) packed -> LDS stride 4 (w-slot unused) ----
    {
        const float* xg = x + (size_t)blockIdx.x * (TT * 3);
        for (int idx = j; idx < TT * 3; idx += 256) {
            int t = idx / 3;              // magic-mul, no HW divide
            int c = idx - 3 * t;
            xs4[t * 4 + c] = xg[idx];
        }
        if (j < 4) xs4[TT * 4 + j] = 0.0f;
    }
    // ---- zero h double-buffers ----
    if (j < 128)       ((float*)h1buf)[j] = 0.0f;
    else               ((float*)h2buf)[j - 128] = 0.0f;

    // ---- thread j's weights: gate j of both layers (192+5 floats, registers) ----
    float wA[64], wB[64], wC[64];   // Whh0 row j | Wih1 row j | Whh1 row j
    {
        const float4* a = (const float4*)(Whh0 + j * 64);
        const float4* b = (const float4*)(Wih1 + j * 64);
        const float4* c = (const float4*)(Whh1 + j * 64);
        #pragma unroll
        for (int k = 0; k < 16; ++k) {
            float4 va = a[k];
            wA[4*k+0] = va.x; wA[4*k+1] = va.y; wA[4*k+2] = va.z; wA[4*k+3] = va.w;
            float4 vb = b[k];
            wB[4*k+0] = vb.x; wB[4*k+1] = vb.y; wB[4*k+2] = vb.z; wB[4*k+3] = vb.w;
            float4 vc = c[k];
            wC[4*k+0] = vc.x; wC[4*k+1] = vc.y; wC[4*k+2] = vc.z; wC[4*k+3] = vc.w;
        }
    }
    const float wx0 = Wih0[j*3+0], wx1 = Wih0[j*3+1], wx2 = Wih0[j*3+2];
    const float bias0 = bih0[j] + bhh0[j];
    const float bias1 = bih1[j] + bhh1[j];

    const int cls = j >> 6;               // 0:i 1:f 2:g 3:o (== wave index, uniform)
    const int uL  = (j >> 6) & 1;         // phase-2: wave0 -> L0, wave1 -> L1
    const int uj  = j & 63;
    float c_state = 0.0f;

    __syncthreads();

    // iter it: L0 computes step it (valid it<TT); L1 computes step it-1 (valid it>=1).
    // Edge iters compute garbage unconditionally on zeroed/in-bounds inputs; only
    // state updates / stores are guarded.
    for (int it = 0; it <= TT; ++it) {
        const int cur  = it & 1;
        const int prev = cur ^ 1;

        // ---------------- phase 1: gate dot-products ----------------
        const float4* h1p = (const float4*)h1buf[prev];   // h1[it-1] (broadcast)
        const float4* h2p = (const float4*)h2buf[cur];    // h2[it-2]

        float Aa=0.f, Ab=0.f;   // L0:  Whh0[j] . h1
        float Ia=0.f, Ib=0.f;   // L1:  Wih1[j] . h1
        float Ha=0.f, Hb=0.f;   // L1:  Whh1[j] . h2
        #pragma unroll
        for (int k = 0; k < 16; ++k) {
            float4 p = h1p[k];
            float4 r = h2p[k];
            Aa = fmaf(wA[4*k+0], p.x, Aa); Ab = fmaf(wA[4*k+1], p.y, Ab);
            Aa = fmaf(wA[4*k+2], p.z, Aa); Ab = fmaf(wA[4*k+3], p.w, Ab);
            Ia = fmaf(wB[4*k+0], p.x, Ia); Ib = fmaf(wB[4*k+1], p.y, Ib);
            Ia = fmaf(wB[4*k+2], p.z, Ia); Ib = fmaf(wB[4*k+3], p.w, Ib);
            Ha = fmaf(wC[4*k+0], r.x, Ha); Hb = fmaf(wC[4*k+1], r.y, Hb);
            Ha = fmaf(wC[4*k+2], r.z, Ha); Hb = fmaf(wC[4*k+3], r.w, Hb);
        }
        float4 xv = ((const float4*)xs4)[it];
        float g0 = bias0 + (Aa + Ab) + wx0*xv.x + wx1*xv.y + wx2*xv.z;
        float g1 = bias1 + (Ia + Ib) + (Ha + Hb);
        if (cls == 2) { g0 = fast_tanh(g0);    g1 = fast_tanh(g1); }
        else          { g0 = fast_sigmoid(g0); g1 = fast_sigmoid(g1); }
        gbuf[0][j] = g0;
        gbuf[1][j] = g1;
        __syncthreads();

        // ---------------- phase 2: state updates (threads 0-127) ----------------
        if (j < 128) {
            if (uL == 0) {
                if (it < TT) {
                    float iv = gbuf[0][      uj];
                    float fv = gbuf[0][ 64 + uj];
                    float gv = gbuf[0][128 + uj];
                    float ov = gbuf[0][192 + uj];
                    c_state = fmaf(fv, c_state, iv * gv);
                    h1buf[cur][uj] = ov * fast_tanh(c_state);       // h1[it]
                }
            } else {
                if (it >= 1) {
                    float iv = gbuf[1][      uj];
                    float fv = gbuf[1][ 64 + uj];
                    float gv = gbuf[1][128 + uj];
                    float ov = gbuf[1][192 + uj];
                    c_state = fmaf(fv, c_state, iv * gv);
                    float hv = ov * fast_tanh(c_state);
                    h2buf[prev][uj] = hv;                           // h2[it-1]
                    if (it == TT)
                        out[(size_t)blockIdx.x * 64 + uj] = hv;
                }
            }
        }
        __syncthreads();
    }
}

extern "C" void kernel_launch(void* const* d_in, const int* in_sizes, int n_in,
                              void* d_out, int out_size, void* d_ws, size_t ws_size,
                              hipStream_t stream) {
    const float* x    = (const float*)d_in[0];
    const float* Wih0 = (const float*)d_in[1];
    const float* Whh0 = (const float*)d_in[2];
    const float* bih0 = (const float*)d_in[3];
    const float* bhh0 = (const float*)d_in[4];
    const float* Wih1 = (const float*)d_in[5];
    const float* Whh1 = (const float*)d_in[6];
    const float* bih1 = (const float*)d_in[7];
    const float* bhh1 = (const float*)d_in[8];
    float* out = (float*)d_out;

    // 512 sequences, 1 per block -> 512 blocks = 2 blocks/CU (2 waves/SIMD for
    // latency hiding); 256 threads (4 waves) keeps the 256-VGPR budget.
    lstm2_fused<<<512, 256, 0, stream>>>(x, Wih0, Whh0, bih0, bhh0,
                                         Wih1, Whh1, bih1, bhh1, out);
}